// Round 1
// baseline (9059.141 us; speedup 1.0000x reference)
//
#include <hip/hip_runtime.h>

#define NHID 128
#define NGRAPHS 512

// broadcast lane k's value of v to all lanes (returns wave-uniform SGPR value)
__device__ __forceinline__ float rdlane(float v, int l) {
    return __uint_as_float((unsigned)__builtin_amdgcn_readlane((int)__float_as_uint(v), l));
}

// ---------------- scatter: agg[dst[e]] += h[src[e]]  (32 lanes/edge, float4) ----
__global__ __launch_bounds__(256) void k_scatter(
    const float* __restrict__ h, const int* __restrict__ src,
    const int* __restrict__ dst, float* __restrict__ agg, int nE)
{
    int t = blockIdx.x * 256 + threadIdx.x;
    int e = t >> 5;
    if (e >= nE) return;
    int lane4 = (t & 31) << 2;
    int s = src[e], d = dst[e];
    const float4 v = *reinterpret_cast<const float4*>(h + (size_t)s * NHID + lane4);
    float* o = agg + (size_t)d * NHID + lane4;
    atomicAdd(o + 0, v.x);
    atomicAdd(o + 1, v.y);
    atomicAdd(o + 2, v.z);
    atomicAdd(o + 3, v.w);
}

// ---------------- fused row GEMM: out = relu((in0 [+ in1]) @ W.T + b) ----------
// W is [128 out][128 in] row-major (torch Linear). Stored in LDS transposed +
// XOR-swizzled: wt[k*128 + (c ^ (k&31))] = W[c][k]  -> conflict-free loads AND
// inner-loop reads (banks = (c^(k&31))%32, distinct across lanes).
// Each wave owns RPW rows; lane holds cols (lane, lane+64); z[k] broadcast via
// v_readlane (no LDS traffic for z).
#define RPW 4

__global__ __launch_bounds__(1024) void k_gemm_relu(
    const float* __restrict__ in0, const float* __restrict__ in1,
    const float* __restrict__ W, const float* __restrict__ b,
    float* __restrict__ out, int nrows)
{
    __shared__ float wt[NHID * NHID];   // 64 KiB exactly
    int tid = threadIdx.x;
    for (int i = 0; i < NHID * NHID; i += 1024) {
        int e = i + tid;
        int c = e >> 7, k = e & 127;
        wt[k * NHID + (c ^ (k & 31))] = W[e];
    }
    __syncthreads();

    int wave = tid >> 6, lane = tid & 63;
    float bc0 = b[lane], bc1 = b[lane + 64];

    const int rows_per_block = 16 * RPW;   // 16 waves
    for (int base = blockIdx.x * rows_per_block + wave * RPW; base < nrows;
         base += gridDim.x * rows_per_block) {
        float z0[RPW], z1[RPW], a0[RPW], a1[RPW];
        #pragma unroll
        for (int r = 0; r < RPW; ++r) {
            int row = base + r;
            bool ok = row < nrows;
            size_t off = (size_t)row * NHID;
            z0[r] = ok ? in0[off + lane] : 0.f;
            z1[r] = ok ? in0[off + lane + 64] : 0.f;
            if (in1) {
                z0[r] += ok ? in1[off + lane] : 0.f;
                z1[r] += ok ? in1[off + lane + 64] : 0.f;
            }
            a0[r] = 0.f; a1[r] = 0.f;
        }
        // k = 0..63 uses z0, k = 64..127 uses z1 (avoids per-k cndmask)
        #pragma unroll 16
        for (int k = 0; k < 64; ++k) {
            int sw = lane ^ (k & 31);
            float w0 = wt[k * NHID + sw];
            float w1 = wt[k * NHID + sw + 64];
            #pragma unroll
            for (int r = 0; r < RPW; ++r) {
                float zk = rdlane(z0[r], k);
                a0[r] = fmaf(zk, w0, a0[r]);
                a1[r] = fmaf(zk, w1, a1[r]);
            }
        }
        #pragma unroll 16
        for (int k = 0; k < 64; ++k) {
            int sw = lane ^ (k & 31);      // ((k+64)&31) == (k&31)
            float w0 = wt[(k + 64) * NHID + sw];
            float w1 = wt[(k + 64) * NHID + sw + 64];
            #pragma unroll
            for (int r = 0; r < RPW; ++r) {
                float zk = rdlane(z1[r], k);
                a0[r] = fmaf(zk, w0, a0[r]);
                a1[r] = fmaf(zk, w1, a1[r]);
            }
        }
        #pragma unroll
        for (int r = 0; r < RPW; ++r) {
            int row = base + r;
            if (row < nrows) {
                size_t off = (size_t)row * NHID;
                out[off + lane]      = fmaxf(a0[r] + bc0, 0.f);
                out[off + lane + 64] = fmaxf(a1[r] + bc1, 0.f);
            }
        }
    }
}

// ---------------- global add pool: pooled[batch[n]] += h[n] --------------------
__global__ __launch_bounds__(256) void k_pool(
    const float* __restrict__ h, const int* __restrict__ batch,
    float* __restrict__ pooled, int nrows)
{
    int t = blockIdx.x * 256 + threadIdx.x;
    int node = t >> 5;
    if (node >= nrows) return;
    int lane4 = (t & 31) << 2;
    int g = batch[node];
    const float4 v = *reinterpret_cast<const float4*>(h + (size_t)node * NHID + lane4);
    float* o = pooled + (size_t)g * NHID + lane4;
    atomicAdd(o + 0, v.x);
    atomicAdd(o + 1, v.y);
    atomicAdd(o + 2, v.z);
    atomicAdd(o + 3, v.w);
}

// ---------------- log_softmax over 128 cols, in place --------------------------
__global__ __launch_bounds__(256) void k_lsm(float* __restrict__ pooled)
{
    int row = blockIdx.x * 4 + (threadIdx.x >> 6);
    int lane = threadIdx.x & 63;
    if (row >= NGRAPHS) return;
    float v0 = pooled[row * NHID + lane];
    float v1 = pooled[row * NHID + lane + 64];
    float m = fmaxf(v0, v1);
    for (int o = 32; o; o >>= 1) m = fmaxf(m, __shfl_xor(m, o, 64));
    float s = expf(v0 - m) + expf(v1 - m);
    for (int o = 32; o; o >>= 1) s += __shfl_xor(s, o, 64);
    float ls = logf(s);
    pooled[row * NHID + lane]      = v0 - m - ls;
    pooled[row * NHID + lane + 64] = v1 - m - ls;
}

extern "C" void kernel_launch(void* const* d_in, const int* in_sizes, int n_in,
                              void* d_out, int out_size, void* d_ws, size_t ws_size,
                              hipStream_t stream)
{
    const float* x   = (const float*)d_in[0];
    const int*   ei  = (const int*)d_in[1];
    const int*   bat = (const int*)d_in[2];
    const float* W1  = (const float*)d_in[3];
    const float* b1  = (const float*)d_in[4];
    const float* W2  = (const float*)d_in[5];
    const float* b2  = (const float*)d_in[6];

    int nE = in_sizes[1] / 2;
    int nN = in_sizes[0] / NHID;
    const int* src = ei;
    const int* dst = ei + nE;

    size_t featElems = (size_t)nN * NHID;
    size_t featBytes = featElems * sizeof(float);
    if (ws_size < 2 * featBytes) return;   // defensive: need 2 x 51.2 MB

    float* bufA = (float*)d_ws;            // h output of each layer
    float* bufB = bufA + featElems;        // agg / hidden scratch

    const float* hcur = x;
    for (int l = 0; l < 3; ++l) {
        hipMemsetAsync(bufB, 0, featBytes, stream);
        {
            long long threads = (long long)nE * 32;
            int blocks = (int)((threads + 255) / 256);
            k_scatter<<<blocks, 256, 0, stream>>>(hcur, src, dst, bufB, nE);
        }
        // hidden = relu((h + agg) @ W1.T + b1)  -> bufB in place (row-local)
        k_gemm_relu<<<256, 1024, 0, stream>>>(hcur, bufB,
            W1 + (size_t)l * NHID * NHID, b1 + (size_t)l * NHID, bufB, nN);
        // h' = relu(hidden @ W2.T + b2) -> bufA
        k_gemm_relu<<<256, 1024, 0, stream>>>(bufB, nullptr,
            W2 + (size_t)l * NHID * NHID, b2 + (size_t)l * NHID, bufA, nN);
        hcur = bufA;
    }

    float* pooled = (float*)d_out;
    hipMemsetAsync(d_out, 0, (size_t)NGRAPHS * NHID * sizeof(float), stream);
    {
        long long threads = (long long)nN * 32;
        int blocks = (int)((threads + 255) / 256);
        k_pool<<<blocks, 256, 0, stream>>>(hcur, bat, pooled, nN);
    }
    k_lsm<<<NGRAPHS / 4, 256, 0, stream>>>(pooled);
}

// Round 3
// 1304.238 us; speedup vs baseline: 6.9459x; 6.9459x over previous
//
#include <hip/hip_runtime.h>

#define NHID 128
#define NGRAPHS 512

__device__ __forceinline__ float rdlane(float v, int l) {
    return __uint_as_float((unsigned)__builtin_amdgcn_readlane((int)__float_as_uint(v), l));
}

// ================= CSR build =================================================
__global__ __launch_bounds__(256) void k_hist(
    const int* __restrict__ dst, int* __restrict__ deg, int nE)
{
    int e = blockIdx.x * 256 + threadIdx.x;
    if (e < nE) atomicAdd(&deg[dst[e]], 1);
}

// phase A: per-256-chunk sums
__global__ __launch_bounds__(256) void k_scan_partial(
    const int* __restrict__ deg, int* __restrict__ partial, int nN)
{
    __shared__ int sm[256];
    int i = blockIdx.x * 256 + threadIdx.x;
    sm[threadIdx.x] = (i < nN) ? deg[i] : 0;
    __syncthreads();
    for (int s = 128; s > 0; s >>= 1) {
        if (threadIdx.x < s) sm[threadIdx.x] += sm[threadIdx.x + s];
        __syncthreads();
    }
    if (threadIdx.x == 0) partial[blockIdx.x] = sm[0];
}

// phase B: single-block exclusive scan of partials (nb <= 512); writes total
__global__ __launch_bounds__(512) void k_scan_top(
    int* __restrict__ partial, int nb, int* __restrict__ rowptr, int nN)
{
    __shared__ int sm[512];
    int v = (threadIdx.x < nb) ? partial[threadIdx.x] : 0;
    sm[threadIdx.x] = v;
    __syncthreads();
    for (int o = 1; o < 512; o <<= 1) {
        int t = (threadIdx.x >= o) ? sm[threadIdx.x - o] : 0;
        __syncthreads();
        sm[threadIdx.x] += t;
        __syncthreads();
    }
    if (threadIdx.x < nb) partial[threadIdx.x] = sm[threadIdx.x] - v;  // exclusive
    if (threadIdx.x == 511) rowptr[nN] = sm[511];                      // total = nE
}

// phase C: per-chunk exclusive scan + chunk offset -> rowptr & cursor
__global__ __launch_bounds__(256) void k_scan_final(
    const int* __restrict__ deg, const int* __restrict__ partial,
    int* __restrict__ rowptr, int* __restrict__ cursor, int nN)
{
    __shared__ int sm[256];
    int i = blockIdx.x * 256 + threadIdx.x;
    int v = (i < nN) ? deg[i] : 0;
    sm[threadIdx.x] = v;
    __syncthreads();
    for (int o = 1; o < 256; o <<= 1) {
        int t = (threadIdx.x >= o) ? sm[threadIdx.x - o] : 0;
        __syncthreads();
        sm[threadIdx.x] += t;
        __syncthreads();
    }
    int excl = sm[threadIdx.x] - v + partial[blockIdx.x];
    if (i < nN) { rowptr[i] = excl; cursor[i] = excl; }
}

__global__ __launch_bounds__(256) void k_fill(
    const int* __restrict__ src, const int* __restrict__ dst,
    int* __restrict__ cursor, int* __restrict__ csr_src, int nE)
{
    int e = blockIdx.x * 256 + threadIdx.x;
    if (e >= nE) return;
    int slot = atomicAdd(&cursor[dst[e]], 1);
    csr_src[slot] = src[e];
}

// ================= gather: z[n] = h[n] + sum_{e in CSR[n]} h[src_e] ==========
// one wave per node; lane holds float2 (features 2l, 2l+1) -> 512B/row coalesced
__global__ __launch_bounds__(256) void k_gather(
    const float* __restrict__ h, const int* __restrict__ rowptr,
    const int* __restrict__ csr_src, float* __restrict__ z, int nN)
{
    int wid = (blockIdx.x * 256 + threadIdx.x) >> 6;
    int lane = threadIdx.x & 63;
    if (wid >= nN) return;
    int beg = rowptr[wid], end = rowptr[wid + 1];
    size_t loff = (size_t)lane * 2;
    float2 acc = *reinterpret_cast<const float2*>(h + (size_t)wid * NHID + loff);
    float2 acc2 = make_float2(0.f, 0.f);
    int e = beg;
    // 4-deep: batch the index loads, then the 4 row loads, to keep VMEM busy
    for (; e + 4 <= end; e += 4) {
        int s0 = csr_src[e], s1 = csr_src[e + 1], s2 = csr_src[e + 2], s3 = csr_src[e + 3];
        float2 v0 = *reinterpret_cast<const float2*>(h + (size_t)s0 * NHID + loff);
        float2 v1 = *reinterpret_cast<const float2*>(h + (size_t)s1 * NHID + loff);
        float2 v2 = *reinterpret_cast<const float2*>(h + (size_t)s2 * NHID + loff);
        float2 v3 = *reinterpret_cast<const float2*>(h + (size_t)s3 * NHID + loff);
        acc.x += v0.x; acc.y += v0.y;
        acc2.x += v1.x; acc2.y += v1.y;
        acc.x += v2.x; acc.y += v2.y;
        acc2.x += v3.x; acc2.y += v3.y;
    }
    for (; e < end; ++e) {
        int s = csr_src[e];
        float2 v = *reinterpret_cast<const float2*>(h + (size_t)s * NHID + loff);
        acc.x += v.x; acc.y += v.y;
    }
    acc.x += acc2.x; acc.y += acc2.y;
    *reinterpret_cast<float2*>(z + (size_t)wid * NHID + loff) = acc;
}

// ================= fused row GEMM: out = relu(in @ W.T + b) ==================
#define RPW 4
__global__ __launch_bounds__(1024) void k_gemm_relu(
    const float* __restrict__ in0, const float* __restrict__ W,
    const float* __restrict__ b, float* __restrict__ out, int nrows)
{
    __shared__ float wt[NHID * NHID];   // 64 KiB, transposed + XOR-swizzled
    int tid = threadIdx.x;
    for (int i = 0; i < NHID * NHID; i += 1024) {
        int e = i + tid;
        int c = e >> 7, k = e & 127;
        wt[k * NHID + (c ^ (k & 31))] = W[e];
    }
    __syncthreads();

    int wave = tid >> 6, lane = tid & 63;
    float bc0 = b[lane], bc1 = b[lane + 64];

    const int rows_per_block = 16 * RPW;
    for (int base = blockIdx.x * rows_per_block + wave * RPW; base < nrows;
         base += gridDim.x * rows_per_block) {
        float z0[RPW], z1[RPW], a0[RPW], a1[RPW];
        #pragma unroll
        for (int r = 0; r < RPW; ++r) {
            int row = base + r;
            bool ok = row < nrows;
            size_t off = (size_t)row * NHID;
            z0[r] = ok ? in0[off + lane] : 0.f;
            z1[r] = ok ? in0[off + lane + 64] : 0.f;
            a0[r] = 0.f; a1[r] = 0.f;
        }
        #pragma unroll 16
        for (int k = 0; k < 64; ++k) {
            int sw = lane ^ (k & 31);
            float w0 = wt[k * NHID + sw];
            float w1 = wt[k * NHID + sw + 64];
            #pragma unroll
            for (int r = 0; r < RPW; ++r) {
                float zk = rdlane(z0[r], k);
                a0[r] = fmaf(zk, w0, a0[r]);
                a1[r] = fmaf(zk, w1, a1[r]);
            }
        }
        #pragma unroll 16
        for (int k = 0; k < 64; ++k) {
            int sw = lane ^ (k & 31);
            float w0 = wt[(k + 64) * NHID + sw];
            float w1 = wt[(k + 64) * NHID + sw + 64];
            #pragma unroll
            for (int r = 0; r < RPW; ++r) {
                float zk = rdlane(z1[r], k);
                a0[r] = fmaf(zk, w0, a0[r]);
                a1[r] = fmaf(zk, w1, a1[r]);
            }
        }
        #pragma unroll
        for (int r = 0; r < RPW; ++r) {
            int row = base + r;
            if (row < nrows) {
                size_t off = (size_t)row * NHID;
                out[off + lane]      = fmaxf(a0[r] + bc0, 0.f);
                out[off + lane + 64] = fmaxf(a1[r] + bc1, 0.f);
            }
        }
    }
}

// ================= segmented pool (batch is sorted) ==========================
__global__ __launch_bounds__(128) void k_pool_seg(
    const float* __restrict__ h, const int* __restrict__ batch,
    float* __restrict__ pooled, int nN)
{
    int g = blockIdx.x;
    int lo = 0, hi = nN;
    while (lo < hi) { int m = (lo + hi) >> 1; if (batch[m] < g) lo = m + 1; else hi = m; }
    int s = lo;
    hi = nN;
    while (lo < hi) { int m = (lo + hi) >> 1; if (batch[m] < g + 1) lo = m + 1; else hi = m; }
    int e = lo;
    float acc = 0.f;
    #pragma unroll 4
    for (int n = s; n < e; ++n) acc += h[(size_t)n * NHID + threadIdx.x];
    pooled[g * NHID + threadIdx.x] = acc;
}

// ================= log_softmax over 128 cols, in place =======================
__global__ __launch_bounds__(256) void k_lsm(float* __restrict__ pooled)
{
    int row = blockIdx.x * 4 + (threadIdx.x >> 6);
    int lane = threadIdx.x & 63;
    if (row >= NGRAPHS) return;
    float v0 = pooled[row * NHID + lane];
    float v1 = pooled[row * NHID + lane + 64];
    float m = fmaxf(v0, v1);
    for (int o = 32; o; o >>= 1) m = fmaxf(m, __shfl_xor(m, o, 64));
    float s = expf(v0 - m) + expf(v1 - m);
    for (int o = 32; o; o >>= 1) s += __shfl_xor(s, o, 64);
    float ls = logf(s);
    pooled[row * NHID + lane]      = v0 - m - ls;
    pooled[row * NHID + lane + 64] = v1 - m - ls;
}

extern "C" void kernel_launch(void* const* d_in, const int* in_sizes, int n_in,
                              void* d_out, int out_size, void* d_ws, size_t ws_size,
                              hipStream_t stream)
{
    const float* x   = (const float*)d_in[0];
    const int*   ei  = (const int*)d_in[1];
    const int*   bat = (const int*)d_in[2];
    const float* W1  = (const float*)d_in[3];
    const float* b1  = (const float*)d_in[4];
    const float* W2  = (const float*)d_in[5];
    const float* b2  = (const float*)d_in[6];

    int nE = in_sizes[1] / 2;
    int nN = in_sizes[0] / NHID;
    const int* src = ei;
    const int* dst = ei + nE;

    size_t featElems = (size_t)nN * NHID;

    // workspace layout
    float* bufA   = (float*)d_ws;                       // 51.2 MB
    float* bufB   = bufA + featElems;                   // 51.2 MB
    int*   rowptr = (int*)(bufB + featElems);           // nN+1
    int*   cursor = rowptr + (nN + 1);                  // nN
    int*   deg    = cursor + nN;                        // nN
    int*   partial= deg + nN;                           // 512
    int*   csr_src= partial + 512;                      // nE
    size_t needed = ((size_t)(csr_src + nE) - (size_t)d_ws);
    if (ws_size < needed) return;

    int nbA = (nN + 255) / 256;        // 391 for 100k  (must be <= 512)

    // ---- CSR build (once per call, reused by all 3 layers) ----
    hipMemsetAsync(deg, 0, (size_t)nN * sizeof(int), stream);
    k_hist<<<(nE + 255) / 256, 256, 0, stream>>>(dst, deg, nE);
    k_scan_partial<<<nbA, 256, 0, stream>>>(deg, partial, nN);
    k_scan_top<<<1, 512, 0, stream>>>(partial, nbA, rowptr, nN);
    k_scan_final<<<nbA, 256, 0, stream>>>(deg, partial, rowptr, cursor, nN);
    k_fill<<<(nE + 255) / 256, 256, 0, stream>>>(src, dst, cursor, csr_src, nE);

    // ---- 3 GIN layers ----
    const float* hcur = x;
    for (int l = 0; l < 3; ++l) {
        int gwaves = (nN * 64 + 255) / 256;
        k_gather<<<gwaves, 256, 0, stream>>>(hcur, rowptr, csr_src, bufB, nN);
        k_gemm_relu<<<256, 1024, 0, stream>>>(bufB,
            W1 + (size_t)l * NHID * NHID, b1 + (size_t)l * NHID, bufB, nN);
        k_gemm_relu<<<256, 1024, 0, stream>>>(bufB,
            W2 + (size_t)l * NHID * NHID, b2 + (size_t)l * NHID, bufA, nN);
        hcur = bufA;
    }

    // ---- pool + log_softmax ----
    float* pooled = (float*)d_out;
    k_pool_seg<<<NGRAPHS, 128, 0, stream>>>(hcur, bat, pooled, nN);
    k_lsm<<<NGRAPHS / 4, 256, 0, stream>>>(pooled);
}

// Round 7
// 894.684 us; speedup vs baseline: 10.1255x; 1.4578x over previous
//
#include <hip/hip_runtime.h>
#include <hip/hip_bf16.h>

#define NHID 128
#define NGRAPHS 512

typedef __attribute__((ext_vector_type(8))) short short8_t;   // 8 bf16 (4 VGPR)
typedef __attribute__((ext_vector_type(4))) float f32x4;      // MFMA C/D

__device__ __forceinline__ ushort f2bf(float x) {
    __hip_bfloat16 h = __float2bfloat16(x);
    return *reinterpret_cast<ushort*>(&h);
}
__device__ __forceinline__ float bf2f(ushort u) {
    __hip_bfloat16 h; *reinterpret_cast<ushort*>(&h) = u;
    return __bfloat162float(h);
}
__device__ __forceinline__ void split2(float x, ushort& hi, ushort& lo) {
    hi = f2bf(x);
    lo = f2bf(x - bf2f(hi));
}

// ================= CSR build =================================================
__global__ __launch_bounds__(256) void k_hist(
    const int* __restrict__ dst, int* __restrict__ deg, int nE)
{
    int e = blockIdx.x * 256 + threadIdx.x;
    if (e < nE) atomicAdd(&deg[dst[e]], 1);
}

__global__ __launch_bounds__(256) void k_scan_partial(
    const int* __restrict__ deg, int* __restrict__ partial, int nN)
{
    __shared__ int sm[256];
    int i = blockIdx.x * 256 + threadIdx.x;
    sm[threadIdx.x] = (i < nN) ? deg[i] : 0;
    __syncthreads();
    for (int s = 128; s > 0; s >>= 1) {
        if (threadIdx.x < s) sm[threadIdx.x] += sm[threadIdx.x + s];
        __syncthreads();
    }
    if (threadIdx.x == 0) partial[blockIdx.x] = sm[0];
}

__global__ __launch_bounds__(512) void k_scan_top(
    int* __restrict__ partial, int nb, int* __restrict__ rowptr, int nN)
{
    __shared__ int sm[512];
    int v = (threadIdx.x < nb) ? partial[threadIdx.x] : 0;
    sm[threadIdx.x] = v;
    __syncthreads();
    for (int o = 1; o < 512; o <<= 1) {
        int t = (threadIdx.x >= o) ? sm[threadIdx.x - o] : 0;
        __syncthreads();
        sm[threadIdx.x] += t;
        __syncthreads();
    }
    if (threadIdx.x < nb) partial[threadIdx.x] = sm[threadIdx.x] - v;
    if (threadIdx.x == 511) rowptr[nN] = sm[511];
}

__global__ __launch_bounds__(256) void k_scan_final(
    const int* __restrict__ deg, const int* __restrict__ partial,
    int* __restrict__ rowptr, int* __restrict__ cursor, int nN)
{
    __shared__ int sm[256];
    int i = blockIdx.x * 256 + threadIdx.x;
    int v = (i < nN) ? deg[i] : 0;
    sm[threadIdx.x] = v;
    __syncthreads();
    for (int o = 1; o < 256; o <<= 1) {
        int t = (threadIdx.x >= o) ? sm[threadIdx.x - o] : 0;
        __syncthreads();
        sm[threadIdx.x] += t;
        __syncthreads();
    }
    int excl = sm[threadIdx.x] - v + partial[blockIdx.x];
    if (i < nN) { rowptr[i] = excl; cursor[i] = excl; }
}

__global__ __launch_bounds__(256) void k_fill(
    const int* __restrict__ src, const int* __restrict__ dst,
    int* __restrict__ cursor, int* __restrict__ csr_src, int nE)
{
    int e = blockIdx.x * 256 + threadIdx.x;
    if (e >= nE) return;
    int slot = atomicAdd(&cursor[dst[e]], 1);
    csr_src[slot] = src[e];
}

// ================= W split/pre-swizzle: 6 mats -> (hi|lo) bf16 ===============
// pos(c,k) = c*128 + (((k>>3) ^ (c&15))<<3 | (k&7))  -> conflict-free b128 reads
__global__ __launch_bounds__(256) void k_wsplit(
    const float* __restrict__ W1, const float* __restrict__ W2,
    ushort* __restrict__ ws)
{
    int idx = blockIdx.x * 256 + threadIdx.x;      // 0..98303
    if (idx >= 6 * 16384) return;
    int mat = idx >> 14;
    int e   = idx & 16383;
    int l = mat >> 1;
    const float* W = (mat & 1) ? W2 : W1;
    float v = W[l * 16384 + e];
    int c = e >> 7, k = e & 127;
    int pos = c * 128 + ((((k >> 3) ^ (c & 15)) << 3) | (k & 7));
    ushort hi, lo; split2(v, hi, lo);
    ushort* base = ws + mat * 32768;
    base[pos] = hi;
    base[16384 + pos] = lo;
}

// ================= gather: z[n] = h[n] + sum h[src]; writes split bf16 =======
__global__ __launch_bounds__(256) void k_gather(
    const float* __restrict__ h, const int* __restrict__ rowptr,
    const int* __restrict__ csr_src,
    ushort* __restrict__ zh, ushort* __restrict__ zl, int nN)
{
    int wid = (blockIdx.x * 256 + threadIdx.x) >> 6;
    int lane = threadIdx.x & 63;
    if (wid >= nN) return;
    int beg = rowptr[wid], end = rowptr[wid + 1];
    size_t loff = (size_t)lane * 2;
    float2 acc = *reinterpret_cast<const float2*>(h + (size_t)wid * NHID + loff);
    float2 acc2 = make_float2(0.f, 0.f);
    int e = beg;
    for (; e + 4 <= end; e += 4) {
        int s0 = csr_src[e], s1 = csr_src[e + 1], s2 = csr_src[e + 2], s3 = csr_src[e + 3];
        float2 v0 = *reinterpret_cast<const float2*>(h + (size_t)s0 * NHID + loff);
        float2 v1 = *reinterpret_cast<const float2*>(h + (size_t)s1 * NHID + loff);
        float2 v2 = *reinterpret_cast<const float2*>(h + (size_t)s2 * NHID + loff);
        float2 v3 = *reinterpret_cast<const float2*>(h + (size_t)s3 * NHID + loff);
        acc.x += v0.x; acc.y += v0.y;
        acc2.x += v1.x; acc2.y += v1.y;
        acc.x += v2.x; acc.y += v2.y;
        acc2.x += v3.x; acc2.y += v3.y;
    }
    for (; e < end; ++e) {
        int s = csr_src[e];
        float2 v = *reinterpret_cast<const float2*>(h + (size_t)s * NHID + loff);
        acc.x += v.x; acc.y += v.y;
    }
    acc.x += acc2.x; acc.y += acc2.y;
    ushort hx, lx, hy, ly;
    split2(acc.x, hx, lx);
    split2(acc.y, hy, ly);
    size_t o = (size_t)wid * NHID + lane * 2;
    *reinterpret_cast<uint*>(zh + o) = (uint)hx | ((uint)hy << 16);
    *reinterpret_cast<uint*>(zl + o) = (uint)lx | ((uint)ly << 16);
}

// ================= MFMA GEMM: out = relu(A @ W.T + b), A = Ah+Al (split) =====
// mfma_f32_16x16x32_bf16: A lane l holds A[l&15][(l>>4)*8+j]; B holds
// B[(l>>4)*8+j][l&15]; C/D: col=l&15, row=(l>>4)*4+r (m89-verified).
// Block: 4 waves; wave = 64 rows x 32 cols (4 row-tiles x 2 col-tiles).
// W (pre-split, pre-swizzled) staged into LDS; A frags read from global.
template<bool OUT_SPLIT>
__global__ __launch_bounds__(256) void k_gemm_mfma(
    const ushort* ah, const ushort* al,
    const ushort* __restrict__ wmat,            // hi[16384] | lo[16384], swizzled
    const float* __restrict__ bias,
    ushort* oh, ushort* ol,                     // OUT_SPLIT (may alias ah/al)
    float* __restrict__ of,                     // !OUT_SPLIT
    int nN, int nstripes)
{
    __shared__ ushort wlds[32768];              // 64 KiB
    for (int i = threadIdx.x; i < 4096; i += 256)
        *reinterpret_cast<short8_t*>(&wlds[i * 8]) =
            *reinterpret_cast<const short8_t*>(&wmat[i * 8]);
    __syncthreads();

    const int wave = threadIdx.x >> 6;
    const int lane = threadIdx.x & 63;
    const int li   = lane & 15;                 // A row / B col within tile
    const int kg8  = (lane >> 4) * 8;           // k sub-offset
    const int colbase = wave * 32;
    const float bc0 = bias[colbase + li];
    const float bc1 = bias[colbase + 16 + li];

    for (int s = blockIdx.x; s < nstripes; s += gridDim.x) {
        const int r0 = s * 64;
        f32x4 acc[4][2] = {};
        #pragma unroll
        for (int ks = 0; ks < 4; ++ks) {
            const int k0 = ks * 32 + kg8;
            const int chunk = k0 >> 3;          // ks*4 + (lane>>4)
            short8_t bh[2], bl[2], axh[4], axl[4];
            #pragma unroll
            for (int ct = 0; ct < 2; ++ct) {
                int c = colbase + ct * 16 + li;          // c & 15 == li
                int bpos = c * 128 + ((chunk ^ li) << 3);
                bh[ct] = *reinterpret_cast<const short8_t*>(&wlds[bpos]);
                bl[ct] = *reinterpret_cast<const short8_t*>(&wlds[16384 + bpos]);
            }
            #pragma unroll
            for (int rt = 0; rt < 4; ++rt) {
                size_t aoff = (size_t)(r0 + rt * 16 + li) * NHID + k0;
                axh[rt] = *reinterpret_cast<const short8_t*>(ah + aoff);
                axl[rt] = *reinterpret_cast<const short8_t*>(al + aoff);
            }
            #pragma unroll
            for (int rt = 0; rt < 4; ++rt)
                #pragma unroll
                for (int ct = 0; ct < 2; ++ct) {
                    acc[rt][ct] = __builtin_amdgcn_mfma_f32_16x16x32_bf16(
                        axh[rt], bh[ct], acc[rt][ct], 0, 0, 0);
                    acc[rt][ct] = __builtin_amdgcn_mfma_f32_16x16x32_bf16(
                        axl[rt], bh[ct], acc[rt][ct], 0, 0, 0);
                    acc[rt][ct] = __builtin_amdgcn_mfma_f32_16x16x32_bf16(
                        axh[rt], bl[ct], acc[rt][ct], 0, 0, 0);
                }
        }
        __syncthreads();   // in-place safety: all waves' A reads are complete
        #pragma unroll
        for (int rt = 0; rt < 4; ++rt) {
            #pragma unroll
            for (int ct = 0; ct < 2; ++ct) {
                const int gcol = colbase + ct * 16 + li;
                const float bc = ct ? bc1 : bc0;
                #pragma unroll
                for (int r = 0; r < 4; ++r) {
                    int grow = r0 + rt * 16 + (lane >> 4) * 4 + r;
                    if (grow < nN) {
                        float v = fmaxf(acc[rt][ct][r] + bc, 0.f);
                        size_t o = (size_t)grow * NHID + gcol;
                        if (OUT_SPLIT) {
                            ushort hi, lo; split2(v, hi, lo);
                            oh[o] = hi; ol[o] = lo;
                        } else {
                            of[o] = v;
                        }
                    }
                }
            }
        }
    }
}

// ================= segmented pool (batch sorted) =============================
__global__ __launch_bounds__(128) void k_pool_seg(
    const float* __restrict__ h, const int* __restrict__ batch,
    float* __restrict__ pooled, int nN)
{
    int g = blockIdx.x;
    int lo = 0, hi = nN;
    while (lo < hi) { int m = (lo + hi) >> 1; if (batch[m] < g) lo = m + 1; else hi = m; }
    int s = lo;
    hi = nN;
    while (lo < hi) { int m = (lo + hi) >> 1; if (batch[m] < g + 1) lo = m + 1; else hi = m; }
    int e = lo;
    float acc = 0.f;
    #pragma unroll 4
    for (int n = s; n < e; ++n) acc += h[(size_t)n * NHID + threadIdx.x];
    pooled[g * NHID + threadIdx.x] = acc;
}

// ================= log_softmax over 128 cols, in place =======================
__global__ __launch_bounds__(256) void k_lsm(float* __restrict__ pooled)
{
    int row = blockIdx.x * 4 + (threadIdx.x >> 6);
    int lane = threadIdx.x & 63;
    if (row >= NGRAPHS) return;
    float v0 = pooled[row * NHID + lane];
    float v1 = pooled[row * NHID + lane + 64];
    float m = fmaxf(v0, v1);
    for (int o = 32; o; o >>= 1) m = fmaxf(m, __shfl_xor(m, o, 64));
    float s = expf(v0 - m) + expf(v1 - m);
    for (int o = 32; o; o >>= 1) s += __shfl_xor(s, o, 64);
    float ls = logf(s);
    pooled[row * NHID + lane]      = v0 - m - ls;
    pooled[row * NHID + lane + 64] = v1 - m - ls;
}

extern "C" void kernel_launch(void* const* d_in, const int* in_sizes, int n_in,
                              void* d_out, int out_size, void* d_ws, size_t ws_size,
                              hipStream_t stream)
{
    const float* x   = (const float*)d_in[0];
    const int*   ei  = (const int*)d_in[1];
    const int*   bat = (const int*)d_in[2];
    const float* W1  = (const float*)d_in[3];
    const float* b1  = (const float*)d_in[4];
    const float* W2  = (const float*)d_in[5];
    const float* b2  = (const float*)d_in[6];

    int nE = in_sizes[1] / 2;
    int nN = in_sizes[0] / NHID;
    const int* src = ei;
    const int* dst = ei + nE;

    size_t featElems = (size_t)nN * NHID;
    size_t featBytes = featElems * sizeof(float);
    size_t padElems  = (size_t)(nN + 64) * NHID;   // 64-row pad for OOB A frags

    char* p = (char*)d_ws;
    float*  bufA   = (float*)p;   p += featBytes;
    ushort* zh     = (ushort*)p;  p += padElems * 2;
    ushort* zl     = (ushort*)p;  p += padElems * 2;
    ushort* wsplit = (ushort*)p;  p += (size_t)6 * 32768 * 2;
    int*    rowptr = (int*)p;     p += (size_t)(nN + 1) * 4;
    int*    cursor = (int*)p;     p += (size_t)nN * 4;
    int*    deg    = (int*)p;     p += (size_t)nN * 4;
    int*    partial= (int*)p;     p += 512 * 4;
    int*    csr_src= (int*)p;     p += (size_t)nE * 4;
    if ((size_t)(p - (char*)d_ws) > ws_size) return;

    int nbA = (nN + 255) / 256;

    // ---- CSR build (once per call) ----
    hipMemsetAsync(deg, 0, (size_t)nN * sizeof(int), stream);
    k_hist<<<(nE + 255) / 256, 256, 0, stream>>>(dst, deg, nE);
    k_scan_partial<<<nbA, 256, 0, stream>>>(deg, partial, nN);
    k_scan_top<<<1, 512, 0, stream>>>(partial, nbA, rowptr, nN);
    k_scan_final<<<nbA, 256, 0, stream>>>(deg, partial, rowptr, cursor, nN);
    k_fill<<<(nE + 255) / 256, 256, 0, stream>>>(src, dst, cursor, csr_src, nE);

    // ---- W split + swizzle (once per call) ----
    k_wsplit<<<384, 256, 0, stream>>>(W1, W2, wsplit);

    // ---- 3 GIN layers ----
    int nstripes = (nN + 63) / 64;
    int gblocks  = 512;
    const float* hcur = x;
    for (int l = 0; l < 3; ++l) {
        int gwaves = (nN * 64 + 255) / 256;
        k_gather<<<gwaves, 256, 0, stream>>>(hcur, rowptr, csr_src, zh, zl, nN);
        // hidden = relu(z @ W1.T + b1): split output, in place over zh/zl
        k_gemm_mfma<true><<<gblocks, 256, 0, stream>>>(
            zh, zl, wsplit + (size_t)(l * 2 + 0) * 32768, b1 + (size_t)l * NHID,
            zh, zl, nullptr, nN, nstripes);
        // h = relu(hidden @ W2.T + b2): f32 output
        k_gemm_mfma<false><<<gblocks, 256, 0, stream>>>(
            zh, zl, wsplit + (size_t)(l * 2 + 1) * 32768, b2 + (size_t)l * NHID,
            nullptr, nullptr, bufA, nN, nstripes);
        hcur = bufA;
    }

    // ---- pool + log_softmax ----
    float* pooled = (float*)d_out;
    k_pool_seg<<<NGRAPHS, 128, 0, stream>>>(hcur, bat, pooled, nN);
    k_lsm<<<NGRAPHS / 4, 256, 0, stream>>>(pooled);
}

// Round 8
// 799.316 us; speedup vs baseline: 11.3336x; 1.1193x over previous
//
#include <hip/hip_runtime.h>
#include <hip/hip_bf16.h>

#define NHID 128
#define NGRAPHS 512

typedef __attribute__((ext_vector_type(8))) short short8_t;   // 8 bf16
typedef __attribute__((ext_vector_type(4))) float f32x4;      // MFMA C/D

__device__ __forceinline__ ushort f2bf(float x) {
    __hip_bfloat16 h = __float2bfloat16(x);
    return *reinterpret_cast<ushort*>(&h);
}
__device__ __forceinline__ float bf2f(ushort u) {
    __hip_bfloat16 h; *reinterpret_cast<ushort*>(&h) = u;
    return __bfloat162float(h);
}
__device__ __forceinline__ void split2(float x, ushort& hi, ushort& lo) {
    hi = f2bf(x);
    lo = f2bf(x - bf2f(hi));
}

// ================= CSR build (XCD-partitioned hist/fill) =====================
// partition p = blockIdx&7 owns dst range [p*chunk, (p+1)*chunk); its deg/
// cursor/csr_src slices stay in one XCD's L2 -> dirty lines written once.
__global__ __launch_bounds__(256) void k_hist(
    const int* __restrict__ dst, int* __restrict__ deg, int nE, int nN)
{
    int part = blockIdx.x & 7;
    int sub  = blockIdx.x >> 3;
    int nsub = gridDim.x >> 3;
    int chunk = (nN + 7) / 8;
    int plo = part * chunk, phi = min(nN, plo + chunk);
    for (int e = sub * 256 + threadIdx.x; e < nE; e += nsub * 256) {
        int d = dst[e];
        if (d >= plo && d < phi) atomicAdd(&deg[d], 1);
    }
}

__global__ __launch_bounds__(256) void k_scan_partial(
    const int* __restrict__ deg, int* __restrict__ partial, int nN)
{
    __shared__ int sm[256];
    int i = blockIdx.x * 256 + threadIdx.x;
    sm[threadIdx.x] = (i < nN) ? deg[i] : 0;
    __syncthreads();
    for (int s = 128; s > 0; s >>= 1) {
        if (threadIdx.x < s) sm[threadIdx.x] += sm[threadIdx.x + s];
        __syncthreads();
    }
    if (threadIdx.x == 0) partial[blockIdx.x] = sm[0];
}

__global__ __launch_bounds__(512) void k_scan_top(
    int* __restrict__ partial, int nb, int* __restrict__ rowptr, int nN)
{
    __shared__ int sm[512];
    int v = (threadIdx.x < nb) ? partial[threadIdx.x] : 0;
    sm[threadIdx.x] = v;
    __syncthreads();
    for (int o = 1; o < 512; o <<= 1) {
        int t = (threadIdx.x >= o) ? sm[threadIdx.x - o] : 0;
        __syncthreads();
        sm[threadIdx.x] += t;
        __syncthreads();
    }
    if (threadIdx.x < nb) partial[threadIdx.x] = sm[threadIdx.x] - v;
    if (threadIdx.x == 511) rowptr[nN] = sm[511];
}

__global__ __launch_bounds__(256) void k_scan_final(
    const int* __restrict__ deg, const int* __restrict__ partial,
    int* __restrict__ rowptr, int* __restrict__ cursor, int nN)
{
    __shared__ int sm[256];
    int i = blockIdx.x * 256 + threadIdx.x;
    int v = (i < nN) ? deg[i] : 0;
    sm[threadIdx.x] = v;
    __syncthreads();
    for (int o = 1; o < 256; o <<= 1) {
        int t = (threadIdx.x >= o) ? sm[threadIdx.x - o] : 0;
        __syncthreads();
        sm[threadIdx.x] += t;
        __syncthreads();
    }
    int excl = sm[threadIdx.x] - v + partial[blockIdx.x];
    if (i < nN) { rowptr[i] = excl; cursor[i] = excl; }
}

__global__ __launch_bounds__(256) void k_fill(
    const int* __restrict__ src, const int* __restrict__ dst,
    int* __restrict__ cursor, int* __restrict__ csr_src, int nE, int nN)
{
    int part = blockIdx.x & 7;
    int sub  = blockIdx.x >> 3;
    int nsub = gridDim.x >> 3;
    int chunk = (nN + 7) / 8;
    int plo = part * chunk, phi = min(nN, plo + chunk);
    for (int e = sub * 256 + threadIdx.x; e < nE; e += nsub * 256) {
        int d = dst[e];
        if (d >= plo && d < phi) {
            int slot = atomicAdd(&cursor[d], 1);
            csr_src[slot] = src[e];
        }
    }
}

// ================= W split: 6 mats -> hi[16384]|lo[16384], LINEAR layout =====
__global__ __launch_bounds__(256) void k_wsplit(
    const float* __restrict__ W1, const float* __restrict__ W2,
    ushort* __restrict__ ws)
{
    int idx = blockIdx.x * 256 + threadIdx.x;      // 0..98303
    if (idx >= 6 * 16384) return;
    int mat = idx >> 14;
    int e   = idx & 16383;
    int l = mat >> 1;
    const float* W = (mat & 1) ? W2 : W1;
    float v = W[l * 16384 + e];
    ushort hi, lo; split2(v, hi, lo);
    ushort* base = ws + mat * 32768;
    base[e] = hi;
    base[16384 + e] = lo;
}

// ================= fused GIN layer: gather -> MLP1 -> MLP2 ===================
// One block = one 64-row stripe, 4 waves.
// Phase 0: gather z = h[row] + sum h[src] into LDS as split bf16, XOR-swizzled:
//          feature-chunk ch (8 elems) of row r stored at position (ch ^ (r&15)).
// Phase 1: hidden = relu(z @ W1.T + b1); A-frags from LDS, B-frags from global
//          (W is L2-resident); result split-bf16 back into the SAME LDS buffer.
// Phase 2: h' = relu(hidden @ W2.T + b2) -> global f32.
// mfma_f32_16x16x32_bf16: A lane l = A[l&15][(l>>4)*8+j]; B lane l =
// B[(l>>4)*8+j][l&15]; D: col=l&15, row=(l>>4)*4+r (m89-verified).
__global__ __launch_bounds__(256) void k_layer(
    const float* __restrict__ hin, const int* __restrict__ rowptr,
    const int* __restrict__ csr_src,
    const ushort* __restrict__ w1s, const float* __restrict__ b1,
    const ushort* __restrict__ w2s, const float* __restrict__ b2,
    float* __restrict__ hout, int nN)
{
    __shared__ ushort zls[2][64 * NHID];        // [hi/lo], 32 KiB total
    const int tid = threadIdx.x;
    const int wave = tid >> 6, lane = tid & 63;
    const int r0 = blockIdx.x * 64;

    // ---- phase 0: gather (wave w owns rows r0+w*16 .. +15) ----
    for (int rr = 0; rr < 16; ++rr) {
        int row = r0 + wave * 16 + rr;
        if (row >= nN) break;
        int beg = rowptr[row], end = rowptr[row + 1];
        const float* hrow = hin + (size_t)row * NHID;
        float2 acc = *reinterpret_cast<const float2*>(hrow + lane * 2);
        float2 acc2 = make_float2(0.f, 0.f);
        int e = beg;
        for (; e + 4 <= end; e += 4) {
            int s0 = csr_src[e], s1 = csr_src[e + 1];
            int s2 = csr_src[e + 2], s3 = csr_src[e + 3];
            float2 v0 = *reinterpret_cast<const float2*>(hin + (size_t)s0 * NHID + lane * 2);
            float2 v1 = *reinterpret_cast<const float2*>(hin + (size_t)s1 * NHID + lane * 2);
            float2 v2 = *reinterpret_cast<const float2*>(hin + (size_t)s2 * NHID + lane * 2);
            float2 v3 = *reinterpret_cast<const float2*>(hin + (size_t)s3 * NHID + lane * 2);
            acc.x += v0.x; acc.y += v0.y;
            acc2.x += v1.x; acc2.y += v1.y;
            acc.x += v2.x; acc.y += v2.y;
            acc2.x += v3.x; acc2.y += v3.y;
        }
        for (; e < end; ++e) {
            int s = csr_src[e];
            float2 v = *reinterpret_cast<const float2*>(hin + (size_t)s * NHID + lane * 2);
            acc.x += v.x; acc.y += v.y;
        }
        acc.x += acc2.x; acc.y += acc2.y;
        ushort hx, lx, hy, ly;
        split2(acc.x, hx, lx);
        split2(acc.y, hy, ly);
        // lane holds features (2*lane, 2*lane+1): chunk = lane>>2, in-chunk = (lane&3)*2
        int lrow = row - r0;
        int off = lrow * NHID + (((lane >> 2) ^ (row & 15)) << 3) + (lane & 3) * 2;
        *reinterpret_cast<uint*>(&zls[0][off]) = (uint)hx | ((uint)hy << 16);
        *reinterpret_cast<uint*>(&zls[1][off]) = (uint)lx | ((uint)ly << 16);
    }
    __syncthreads();

    const int li = lane & 15;          // A row (within 16) / B,D col (within 16)
    const int kq = lane >> 4;          // k-quarter 0..3
    const int colbase = wave * 32;

    // ---- phase 1: hidden = relu(z @ W1.T + b1) ----
    {
        const float bc0 = b1[colbase + li], bc1 = b1[colbase + 16 + li];
        f32x4 acc[4][2] = {};
        #pragma unroll
        for (int ks = 0; ks < 4; ++ks) {
            const int chunk = ks * 4 + kq;
            short8_t ah_[4], al_[4], bh_[2], bl_[2];
            #pragma unroll
            for (int rt = 0; rt < 4; ++rt) {
                int posA = (rt * 16 + li) * NHID + ((chunk ^ li) << 3);
                ah_[rt] = *reinterpret_cast<short8_t*>(&zls[0][posA]);
                al_[rt] = *reinterpret_cast<short8_t*>(&zls[1][posA]);
            }
            #pragma unroll
            for (int ct = 0; ct < 2; ++ct) {
                const ushort* wb = w1s + (colbase + ct * 16 + li) * NHID + chunk * 8;
                bh_[ct] = *reinterpret_cast<const short8_t*>(wb);
                bl_[ct] = *reinterpret_cast<const short8_t*>(wb + 16384);
            }
            #pragma unroll
            for (int rt = 0; rt < 4; ++rt)
                #pragma unroll
                for (int ct = 0; ct < 2; ++ct) {
                    acc[rt][ct] = __builtin_amdgcn_mfma_f32_16x16x32_bf16(
                        ah_[rt], bh_[ct], acc[rt][ct], 0, 0, 0);
                    acc[rt][ct] = __builtin_amdgcn_mfma_f32_16x16x32_bf16(
                        al_[rt], bh_[ct], acc[rt][ct], 0, 0, 0);
                    acc[rt][ct] = __builtin_amdgcn_mfma_f32_16x16x32_bf16(
                        ah_[rt], bl_[ct], acc[rt][ct], 0, 0, 0);
                }
        }
        __syncthreads();   // all z reads done -> safe to overwrite LDS
        #pragma unroll
        for (int rt = 0; rt < 4; ++rt)
            #pragma unroll
            for (int ct = 0; ct < 2; ++ct) {
                const int col = colbase + ct * 16 + li;
                const float bc = ct ? bc1 : bc0;
                #pragma unroll
                for (int r = 0; r < 4; ++r) {
                    int lrow = rt * 16 + kq * 4 + r;
                    float v = fmaxf(acc[rt][ct][r] + bc, 0.f);
                    ushort hi, lo; split2(v, hi, lo);
                    int pos = lrow * NHID + ((((col >> 3) ^ (lrow & 15)) << 3) | (col & 7));
                    zls[0][pos] = hi;
                    zls[1][pos] = lo;
                }
            }
    }
    __syncthreads();

    // ---- phase 2: h' = relu(hidden @ W2.T + b2) -> global f32 ----
    {
        const float bc0 = b2[colbase + li], bc1 = b2[colbase + 16 + li];
        f32x4 acc[4][2] = {};
        #pragma unroll
        for (int ks = 0; ks < 4; ++ks) {
            const int chunk = ks * 4 + kq;
            short8_t ah_[4], al_[4], bh_[2], bl_[2];
            #pragma unroll
            for (int rt = 0; rt < 4; ++rt) {
                int posA = (rt * 16 + li) * NHID + ((chunk ^ li) << 3);
                ah_[rt] = *reinterpret_cast<short8_t*>(&zls[0][posA]);
                al_[rt] = *reinterpret_cast<short8_t*>(&zls[1][posA]);
            }
            #pragma unroll
            for (int ct = 0; ct < 2; ++ct) {
                const ushort* wb = w2s + (colbase + ct * 16 + li) * NHID + chunk * 8;
                bh_[ct] = *reinterpret_cast<const short8_t*>(wb);
                bl_[ct] = *reinterpret_cast<const short8_t*>(wb + 16384);
            }
            #pragma unroll
            for (int rt = 0; rt < 4; ++rt)
                #pragma unroll
                for (int ct = 0; ct < 2; ++ct) {
                    acc[rt][ct] = __builtin_amdgcn_mfma_f32_16x16x32_bf16(
                        ah_[rt], bh_[ct], acc[rt][ct], 0, 0, 0);
                    acc[rt][ct] = __builtin_amdgcn_mfma_f32_16x16x32_bf16(
                        al_[rt], bh_[ct], acc[rt][ct], 0, 0, 0);
                    acc[rt][ct] = __builtin_amdgcn_mfma_f32_16x16x32_bf16(
                        ah_[rt], bl_[ct], acc[rt][ct], 0, 0, 0);
                }
        }
        #pragma unroll
        for (int rt = 0; rt < 4; ++rt)
            #pragma unroll
            for (int ct = 0; ct < 2; ++ct) {
                const int col = colbase + ct * 16 + li;
                const float bc = ct ? bc1 : bc0;
                #pragma unroll
                for (int r = 0; r < 4; ++r) {
                    int grow = r0 + rt * 16 + kq * 4 + r;
                    if (grow < nN)
                        hout[(size_t)grow * NHID + col] = fmaxf(acc[rt][ct][r] + bc, 0.f);
                }
            }
    }
}

// ================= segmented pool (batch sorted) =============================
__global__ __launch_bounds__(128) void k_pool_seg(
    const float* __restrict__ h, const int* __restrict__ batch,
    float* __restrict__ pooled, int nN)
{
    int g = blockIdx.x;
    int lo = 0, hi = nN;
    while (lo < hi) { int m = (lo + hi) >> 1; if (batch[m] < g) lo = m + 1; else hi = m; }
    int s = lo;
    hi = nN;
    while (lo < hi) { int m = (lo + hi) >> 1; if (batch[m] < g + 1) lo = m + 1; else hi = m; }
    int e = lo;
    float acc = 0.f;
    #pragma unroll 4
    for (int n = s; n < e; ++n) acc += h[(size_t)n * NHID + threadIdx.x];
    pooled[g * NHID + threadIdx.x] = acc;
}

// ================= log_softmax over 128 cols, in place =======================
__global__ __launch_bounds__(256) void k_lsm(float* __restrict__ pooled)
{
    int row = blockIdx.x * 4 + (threadIdx.x >> 6);
    int lane = threadIdx.x & 63;
    if (row >= NGRAPHS) return;
    float v0 = pooled[row * NHID + lane];
    float v1 = pooled[row * NHID + lane + 64];
    float m = fmaxf(v0, v1);
    for (int o = 32; o; o >>= 1) m = fmaxf(m, __shfl_xor(m, o, 64));
    float s = expf(v0 - m) + expf(v1 - m);
    for (int o = 32; o; o >>= 1) s += __shfl_xor(s, o, 64);
    float ls = logf(s);
    pooled[row * NHID + lane]      = v0 - m - ls;
    pooled[row * NHID + lane + 64] = v1 - m - ls;
}

extern "C" void kernel_launch(void* const* d_in, const int* in_sizes, int n_in,
                              void* d_out, int out_size, void* d_ws, size_t ws_size,
                              hipStream_t stream)
{
    const float* x   = (const float*)d_in[0];
    const int*   ei  = (const int*)d_in[1];
    const int*   bat = (const int*)d_in[2];
    const float* W1  = (const float*)d_in[3];
    const float* b1  = (const float*)d_in[4];
    const float* W2  = (const float*)d_in[5];
    const float* b2  = (const float*)d_in[6];

    int nE = in_sizes[1] / 2;
    int nN = in_sizes[0] / NHID;
    const int* src = ei;
    const int* dst = ei + nE;

    size_t featElems = (size_t)nN * NHID;

    char* p = (char*)d_ws;
    float*  hA     = (float*)p;   p += featElems * 4;
    float*  hB     = (float*)p;   p += featElems * 4;
    ushort* wsplit = (ushort*)p;  p += (size_t)6 * 32768 * 2;
    int*    rowptr = (int*)p;     p += (size_t)(nN + 1) * 4;
    int*    cursor = (int*)p;     p += (size_t)nN * 4;
    int*    deg    = (int*)p;     p += (size_t)nN * 4;
    int*    partial= (int*)p;     p += 512 * 4;
    int*    csr_src= (int*)p;     p += (size_t)nE * 4;
    if ((size_t)(p - (char*)d_ws) > ws_size) return;

    int nbA = (nN + 255) / 256;

    // ---- CSR build (once per call) ----
    hipMemsetAsync(deg, 0, (size_t)nN * sizeof(int), stream);
    k_hist<<<1024, 256, 0, stream>>>(dst, deg, nE, nN);
    k_scan_partial<<<nbA, 256, 0, stream>>>(deg, partial, nN);
    k_scan_top<<<1, 512, 0, stream>>>(partial, nbA, rowptr, nN);
    k_scan_final<<<nbA, 256, 0, stream>>>(deg, partial, rowptr, cursor, nN);
    k_fill<<<1024, 256, 0, stream>>>(src, dst, cursor, csr_src, nE, nN);

    // ---- W split (once per call) ----
    k_wsplit<<<384, 256, 0, stream>>>(W1, W2, wsplit);

    // ---- 3 fused GIN layers: x -> hA -> hB -> hA ----
    int nstripes = (nN + 63) / 64;
    const float* hin = x;
    float* hout = hA;
    for (int l = 0; l < 3; ++l) {
        k_layer<<<nstripes, 256, 0, stream>>>(
            hin, rowptr, csr_src,
            wsplit + (size_t)(l * 2 + 0) * 32768, b1 + (size_t)l * NHID,
            wsplit + (size_t)(l * 2 + 1) * 32768, b2 + (size_t)l * NHID,
            hout, nN);
        hin = hout;
        hout = (hout == hA) ? hB : hA;
    }

    // ---- pool + log_softmax ----
    float* pooled = (float*)d_out;
    k_pool_seg<<<NGRAPHS, 128, 0, stream>>>(hin, bat, pooled, nN);
    k_lsm<<<NGRAPHS / 4, 256, 0, stream>>>(pooled);
}